// Round 17
// baseline (368.058 us; speedup 1.0000x reference)
//
#include <hip/hip_runtime.h>
#include <math.h>

typedef short bf8 __attribute__((ext_vector_type(8)));     // 8 bf16 (4 VGPRs)
typedef _Float16 h8 __attribute__((ext_vector_type(8)));   // 8 f16  (4 VGPRs)
typedef float f4 __attribute__((ext_vector_type(4)));
typedef unsigned short ushort_t;

#define BRANGE 128  // nodes per bucket (dst>>7)
#define NB_E 256    // blocks for edge hist/scatter

// ---------------- helpers ----------------
__device__ __forceinline__ int ilanebcast(int v, int l) {
  return __builtin_amdgcn_readlane(v, l);
}

__device__ __forceinline__ float wave_sum(float v) {
#pragma unroll
  for (int off = 32; off > 0; off >>= 1) v += __shfl_xor(v, off, 64);
  return v;
}

__device__ __forceinline__ ushort_t f2bf(float x) {  // RNE fp32->bf16 bits
  unsigned int u = __float_as_uint(x);
  return (ushort_t)((u + 0x7fffu + ((u >> 16) & 1u)) >> 16);
}
__device__ __forceinline__ float b2f(ushort_t h) {
  return __uint_as_float(((unsigned int)h) << 16);
}

// ================= contention-free bucketed CSR build =================
__global__ __launch_bounds__(256) void k_ehist(const int* __restrict__ dst,
                                               int* __restrict__ bhistT, int E, int nbuk) {
  __shared__ int h[512];
  int b = blockIdx.x, tid = threadIdx.x;
  for (int i = tid; i < nbuk; i += 256) h[i] = 0;
  __syncthreads();
  int chunk = (E + gridDim.x - 1) / gridDim.x;
  int e0 = b * chunk, e1 = min(E, e0 + chunk);
  for (int e = e0 + tid; e < e1; e += 256) atomicAdd(&h[dst[e] >> 7], 1);
  __syncthreads();
  for (int i = tid; i < nbuk; i += 256) bhistT[i * NB_E + b] = h[i];
}

__global__ __launch_bounds__(256) void k_btot(const int* __restrict__ bhistT,
                                              int* __restrict__ bcnt, int nb) {
  __shared__ int sm[256];
  int b = blockIdx.x, tid = threadIdx.x;
  sm[tid] = (tid < nb) ? bhistT[b * NB_E + tid] : 0;
  __syncthreads();
  for (int off = 128; off > 0; off >>= 1) {
    if (tid < off) sm[tid] += sm[tid + off];
    __syncthreads();
  }
  if (tid == 0) bcnt[b] = sm[0];
}

__global__ __launch_bounds__(512) void k_bscan(
    const int* __restrict__ bcnt, int* __restrict__ edgebase, int nbuk,
    int* __restrict__ rowstart, int n, int E) {
  __shared__ int smem[512];
  int t = threadIdx.x;
  int v = (t < nbuk) ? bcnt[t] : 0;
  smem[t] = v;
  __syncthreads();
  for (int off = 1; off < 512; off <<= 1) {
    int u = (t >= off) ? smem[t - off] : 0;
    __syncthreads();
    smem[t] += u;
    __syncthreads();
  }
  if (t < nbuk) edgebase[t] = smem[t] - v;
  if (t == 0) rowstart[n] = E + n;
}

__global__ __launch_bounds__(256) void k_bbase(int* __restrict__ bhistT,
                                               const int* __restrict__ edgebase,
                                               int nb) {
  __shared__ int sm[256];
  int b = blockIdx.x, tid = threadIdx.x;
  int v = (tid < nb) ? bhistT[b * NB_E + tid] : 0;
  sm[tid] = v;
  __syncthreads();
  for (int off = 1; off < 256; off <<= 1) {
    int u = (tid >= off) ? sm[tid - off] : 0;
    __syncthreads();
    sm[tid] += u;
    __syncthreads();
  }
  if (tid < nb) bhistT[b * NB_E + tid] = edgebase[b] + sm[tid] - v;
}

__global__ __launch_bounds__(256) void k_ebucket(
    const int* __restrict__ es, const int* __restrict__ ed,
    const int* __restrict__ bhistT, int* __restrict__ bedges, int E, int nbuk) {
  __shared__ int cur[512];
  int b = blockIdx.x, tid = threadIdx.x;
  for (int i = tid; i < nbuk; i += 256) cur[i] = bhistT[i * NB_E + b];
  __syncthreads();
  int chunk = (E + gridDim.x - 1) / gridDim.x;
  int e0 = b * chunk, e1 = min(E, e0 + chunk);
  for (int e = e0 + tid; e < e1; e += 256) {
    int s = es[e], d = ed[e];
    int pos = atomicAdd(&cur[d >> 7], 1);
    bedges[pos] = (s << 7) | (d & 127);
  }
}

__global__ __launch_bounds__(256) void k_ebsort(
    const int* __restrict__ bedges, const int* __restrict__ edgebase,
    const int* __restrict__ bcnt, int* __restrict__ colidx,
    int* __restrict__ rowstart, float* __restrict__ dinv, int n) {
  __shared__ int h[128];
  __shared__ int c[128];
  int b = blockIdx.x, tid = threadIdx.x;
  int nodes0 = b * BRANGE;
  int nnode = min(BRANGE, n - nodes0);
  int ebase = edgebase[b], ecnt = bcnt[b];
  int colbase = ebase + nodes0;
  if (tid < 128) h[tid] = (tid < nnode) ? 1 : 0;  // self-loop
  __syncthreads();
  for (int k = ebase + tid; k < ebase + ecnt; k += 256)
    atomicAdd(&h[bedges[k] & 127], 1);
  __syncthreads();
  int own = (tid < 128) ? h[tid] : 0;
  for (int off = 1; off < 128; off <<= 1) {
    int t = (tid >= off && tid < 128) ? h[tid - off] : 0;
    __syncthreads();
    if (tid < 128) h[tid] += t;
    __syncthreads();
  }
  if (tid < nnode) {
    int excl = h[tid] - own;
    int node = nodes0 + tid;
    rowstart[node] = colbase + excl;
    dinv[node] = 1.0f / sqrtf((float)own);
    colidx[colbase + excl] = node;  // self-loop first
    c[tid] = excl + 1;
  }
  __syncthreads();
  for (int k = ebase + tid; k < ebase + ecnt; k += 256) {
    int p = bedges[k];
    int pos = atomicAdd(&c[p & 127], 1);
    colidx[colbase + pos] = p >> 7;
  }
}

// ---------------- fused weight swizzles (one kernel, 16 blocks) -------------
__global__ __launch_bounds__(256) void k_wswz_all(
    const float* __restrict__ W0, ushort_t* __restrict__ B0h, ushort_t* __restrict__ B0l,
    const float* __restrict__ W1, _Float16* __restrict__ Bw1h, _Float16* __restrict__ Bw1l,
    const float* __restrict__ W2, _Float16* __restrict__ Bw2h, _Float16* __restrict__ Bw2l,
    const float* __restrict__ Wg, _Float16* __restrict__ Bgh, _Float16* __restrict__ Bgl) {
  int bid = blockIdx.x, tid = threadIdx.x;
  if (bid < 4) {
    int e = bid * 256 + tid;
    int lane = e & 63, kc = (e >> 6) & 3, ct = e >> 8;
    int k0 = kc * 32 + (lane >> 4) * 8;
    int col = ct * 16 + (lane & 15);
#pragma unroll
    for (int j = 0; j < 8; j++) {
      float w = W0[(k0 + j) * 64 + col];
      ushort_t h = f2bf(w);
      B0h[(size_t)e * 8 + j] = h;
      B0l[(size_t)e * 8 + j] = f2bf(w - b2f(h));
    }
  } else if (bid < 8) {
    const float* W = (bid < 6) ? W1 : W2;
    _Float16* Bh = (bid < 6) ? Bw1h : Bw2h;
    _Float16* Bl = (bid < 6) ? Bw1l : Bw2l;
    int e = ((bid - 4) & 1) * 256 + tid;
    int lane = e & 63, kc = (e >> 6) & 1, ct = e >> 7;
    int k0 = kc * 32 + (lane >> 4) * 8;
    int col = ct * 16 + (lane & 15);
#pragma unroll
    for (int j = 0; j < 8; j++) {
      float w = W[(k0 + j) * 64 + col];
      _Float16 h = (_Float16)w;
      Bh[(size_t)e * 8 + j] = h;
      Bl[(size_t)e * 8 + j] = (_Float16)(w - (float)h);
    }
  } else {
    int e = (bid - 8) * 256 + tid;
    int lane = e & 63, kc = (e >> 6) & 7, ct = e >> 9;
    int k0 = kc * 32 + (lane >> 4) * 8;
    int col = ct * 16 + (lane & 15);
#pragma unroll
    for (int j = 0; j < 8; j++) {
      int k = k0 + j;
      float w = Wg[(k & 63) * 256 + (k >> 6) * 64 + col];
      _Float16 h = (_Float16)w;
      Bgh[(size_t)e * 8 + j] = h;
      Bgl[(size_t)e * 8 + j] = (_Float16)(w - (float)h);
    }
  }
}

// ---------------- fused q prep ----------------
__global__ __launch_bounds__(256) void k_qprep(
    const float* __restrict__ W, const float* __restrict__ att_s,
    const float* __restrict__ att_d, _Float16* __restrict__ Bq) {
  __shared__ float qs[256], qd[256];
  int t = threadIdx.x;
  int h = t >> 6, k = t & 63;
  float ss = 0.0f, sd = 0.0f;
  for (int c = 0; c < 64; c++) {
    float w = W[k * 256 + h * 64 + c];
    ss = fmaf(w, att_s[h * 64 + c], ss);
    sd = fmaf(w, att_d[h * 64 + c], sd);
  }
  qs[h * 64 + k] = ss;
  qd[h * 64 + k] = sd;
  __syncthreads();
  if (t < 128) {
    int lane = t & 63, kc = t >> 6;
    int k0 = kc * 32 + (lane >> 4) * 8;
    int col = lane & 15;
#pragma unroll
    for (int j = 0; j < 8; j++) {
      int kk = k0 + j;
      float v = (col < 4) ? qs[col * 64 + kk]
                          : ((col < 8) ? qd[(col - 4) * 64 + kk] : 0.0f);
      Bq[(size_t)t * 8 + j] = (_Float16)v;
    }
  }
}

// ---------------- K1: H0'[N,64] = f16(dinv[n] * (X[N,128] @ W0)) via MFMA --
__global__ __launch_bounds__(256) void k_gemm0_mfma(
    const float* __restrict__ X, const ushort_t* __restrict__ Bh,
    const ushort_t* __restrict__ Bl, const float* __restrict__ dinv,
    _Float16* __restrict__ H, int n, int ntiles) {
  int tid = threadIdx.x, lane = tid & 63, wave = tid >> 6;
  int m = lane & 15, q = lane >> 4;
  for (int tile = blockIdx.x * 4 + wave; tile < ntiles; tile += gridDim.x * 4) {
    int ra = tile * 16 + m;
    if (ra >= n) ra = n - 1;
    const float* xrow = X + (size_t)ra * 128;
    f4 acc[4];
#pragma unroll
    for (int ct = 0; ct < 4; ct++) acc[ct] = (f4){0.f, 0.f, 0.f, 0.f};
#pragma unroll 2
    for (int kc = 0; kc < 4; kc++) {
      int ko = kc * 32 + q * 8;
      float4 xa = *(const float4*)(xrow + ko);
      float4 xb = *(const float4*)(xrow + ko + 4);
      float f[8] = {xa.x, xa.y, xa.z, xa.w, xb.x, xb.y, xb.z, xb.w};
      union { ushort_t u[8]; bf8 v; } Uh, Ul;
#pragma unroll
      for (int j = 0; j < 8; j++) {
        ushort_t h = f2bf(f[j]);
        Uh.u[j] = h;
        Ul.u[j] = f2bf(f[j] - b2f(h));
      }
#pragma unroll
      for (int ct = 0; ct < 4; ct++) {
        size_t boff = ((size_t)(ct * 4 + kc) * 64 + lane) * 8;
        bf8 bh = *(const bf8*)(Bh + boff);
        bf8 bl = *(const bf8*)(Bl + boff);
        acc[ct] = __builtin_amdgcn_mfma_f32_16x16x32_bf16(Uh.v, bh, acc[ct], 0, 0, 0);
        acc[ct] = __builtin_amdgcn_mfma_f32_16x16x32_bf16(Ul.v, bh, acc[ct], 0, 0, 0);
        acc[ct] = __builtin_amdgcn_mfma_f32_16x16x32_bf16(Uh.v, bl, acc[ct], 0, 0, 0);
      }
    }
#pragma unroll
    for (int r = 0; r < 4; r++) {
      int row = tile * 16 + q * 4 + r;
      if (row < n) {
        float dv = dinv[row];
#pragma unroll
        for (int ct = 0; ct < 4; ct++)
          H[(size_t)row * 64 + ct * 16 + m] = (_Float16)(acc[ct][r] * dv);
      }
    }
  }
}

// ---------------- gather core (f16 rows, 32-bit offsets, unroll 8) ----------
__device__ __forceinline__ float gather_sum(const _Float16* __restrict__ h_in,
                                            const int* __restrict__ colidx,
                                            int s0, int s1, int lane) {
  float acc = 0.0f, accB = 0.0f;
  for (int base = s0; base < s1; base += 64) {
    int cnt = min(64, s1 - base);
    int myidx = (lane < cnt) ? colidx[base + lane] : 0;
    int k = 0;
    for (; k + 7 < cnt; k += 8) {
      int i0 = (ilanebcast(myidx, k) << 6) + lane;
      int i1 = (ilanebcast(myidx, k + 1) << 6) + lane;
      int i2 = (ilanebcast(myidx, k + 2) << 6) + lane;
      int i3 = (ilanebcast(myidx, k + 3) << 6) + lane;
      int i4 = (ilanebcast(myidx, k + 4) << 6) + lane;
      int i5 = (ilanebcast(myidx, k + 5) << 6) + lane;
      int i6 = (ilanebcast(myidx, k + 6) << 6) + lane;
      int i7 = (ilanebcast(myidx, k + 7) << 6) + lane;
      float v0 = (float)h_in[i0];
      float v1 = (float)h_in[i1];
      float v2 = (float)h_in[i2];
      float v3 = (float)h_in[i3];
      float v4 = (float)h_in[i4];
      float v5 = (float)h_in[i5];
      float v6 = (float)h_in[i6];
      float v7 = (float)h_in[i7];
      acc += v0; accB += v1; acc += v2; accB += v3;
      acc += v4; accB += v5; acc += v6; accB += v7;
    }
    for (; k + 3 < cnt; k += 4) {
      int i0 = (ilanebcast(myidx, k) << 6) + lane;
      int i1 = (ilanebcast(myidx, k + 1) << 6) + lane;
      int i2 = (ilanebcast(myidx, k + 2) << 6) + lane;
      int i3 = (ilanebcast(myidx, k + 3) << 6) + lane;
      acc += (float)h_in[i0]; accB += (float)h_in[i1];
      acc += (float)h_in[i2]; accB += (float)h_in[i3];
    }
    for (; k < cnt; k++) {
      int i0 = (ilanebcast(myidx, k) << 6) + lane;
      acc += (float)h_in[i0];
    }
  }
  return acc + accB;
}

// ---------------- K2/K3: persistent 16-wave blocks + MFMA GEMV -------------
__global__ __launch_bounds__(1024) void k_agg_gemm_mfma(
    const _Float16* __restrict__ h_in, const float* __restrict__ dinv,
    const int* __restrict__ rowstart, const int* __restrict__ colidx,
    const float* __restrict__ bias, const _Float16* __restrict__ Bh,
    const _Float16* __restrict__ Bl, _Float16* __restrict__ h_out,
    int n, int ntiles) {
  __shared__ __align__(16) _Float16 xstage[16][72];
  int tid = threadIdx.x, lane = tid & 63, w = tid >> 6;
  for (int tile = blockIdx.x; tile < ntiles; tile += gridDim.x) {
    int node = tile * 16 + w;
    float xv = 0.0f;
    if (node < n) {
      int s0 = rowstart[node], s1 = rowstart[node + 1];
      float a = gather_sum(h_in, colidx, s0, s1, lane);
      xv = fmaxf(fmaf(dinv[node], a, bias[lane]), 0.0f);
    }
    xstage[w][lane] = (_Float16)xv;
    __syncthreads();
    if (w < 4) {
      int m = lane & 15, q = lane >> 4, ct = w;
      h8 af0 = *(const h8*)&xstage[m][q * 8];
      h8 af1 = *(const h8*)&xstage[m][32 + q * 8];
      size_t o0 = ((size_t)(ct * 2 + 0) * 64 + lane) * 8;
      size_t o1 = ((size_t)(ct * 2 + 1) * 64 + lane) * 8;
      h8 bh0 = *(const h8*)(Bh + o0);
      h8 bh1 = *(const h8*)(Bh + o1);
      h8 bl0 = *(const h8*)(Bl + o0);
      h8 bl1 = *(const h8*)(Bl + o1);
      f4 acc = (f4){0.f, 0.f, 0.f, 0.f};
      acc = __builtin_amdgcn_mfma_f32_16x16x32_f16(af0, bh0, acc, 0, 0, 0);
      acc = __builtin_amdgcn_mfma_f32_16x16x32_f16(af1, bh1, acc, 0, 0, 0);
      acc = __builtin_amdgcn_mfma_f32_16x16x32_f16(af0, bl0, acc, 0, 0, 0);
      acc = __builtin_amdgcn_mfma_f32_16x16x32_f16(af1, bl1, acc, 0, 0, 0);
#pragma unroll
      for (int r = 0; r < 4; r++) {
        int n2 = tile * 16 + q * 4 + r;
        if (n2 < n)
          h_out[(size_t)n2 * 64 + ct * 16 + m] = (_Float16)(acc[r] * dinv[n2]);
      }
    }
    __syncthreads();
  }
}

// ---------------- K4: persistent 16-wave blocks -> x3 + logits -------------
__global__ __launch_bounds__(1024) void k_agg_gatpre_mfma(
    const _Float16* __restrict__ h_in, const float* __restrict__ dinv,
    const int* __restrict__ rowstart, const int* __restrict__ colidx,
    const float* __restrict__ bias, const _Float16* __restrict__ Bq,
    _Float16* __restrict__ x3, float* __restrict__ a_src, float* __restrict__ a_dst,
    int n, int ntiles) {
  __shared__ __align__(16) _Float16 xstage[16][72];
  int tid = threadIdx.x, lane = tid & 63, w = tid >> 6;
  for (int tile = blockIdx.x; tile < ntiles; tile += gridDim.x) {
    int node = tile * 16 + w;
    float xv = 0.0f;
    if (node < n) {
      int s0 = rowstart[node], s1 = rowstart[node + 1];
      float a = gather_sum(h_in, colidx, s0, s1, lane);
      xv = fmaxf(fmaf(dinv[node], a, bias[lane]), 0.0f);
      x3[(node << 6) + lane] = (_Float16)xv;
    }
    xstage[w][lane] = (_Float16)xv;
    __syncthreads();
    if (w == 0) {
      int m = lane & 15, q = lane >> 4;
      h8 af0 = *(const h8*)&xstage[m][q * 8];
      h8 af1 = *(const h8*)&xstage[m][32 + q * 8];
      h8 bq0 = *(const h8*)(Bq + (size_t)lane * 8);
      h8 bq1 = *(const h8*)(Bq + (size_t)(64 + lane) * 8);
      f4 accL = (f4){0.f, 0.f, 0.f, 0.f};
      accL = __builtin_amdgcn_mfma_f32_16x16x32_f16(af0, bq0, accL, 0, 0, 0);
      accL = __builtin_amdgcn_mfma_f32_16x16x32_f16(af1, bq1, accL, 0, 0, 0);
#pragma unroll
      for (int r = 0; r < 4; r++) {
        int n2 = tile * 16 + q * 4 + r;
        if (n2 < n) {
          if (m < 4) a_src[(size_t)n2 * 4 + m] = accL[r];
          else if (m < 8) a_dst[(size_t)n2 * 4 + (m - 4)] = accL[r];
        }
      }
    }
    __syncthreads();
  }
}

// ---------------- K5 fused: persistent GAT softmax-aggregate + projection --
__global__ __launch_bounds__(1024) void k_gat_fused(
    const _Float16* __restrict__ x3, const float* __restrict__ a_src,
    const float* __restrict__ a_dst, const int* __restrict__ rowstart,
    const int* __restrict__ colidx, const _Float16* __restrict__ Bh,
    const _Float16* __restrict__ Bl, const float* __restrict__ bias,
    float* __restrict__ out, int n, int ntiles) {
  __shared__ __align__(16) float4 wlds[16][64];   // 16 KB
  __shared__ float astage[16][261];               // 16.7 KB
  int tid = threadIdx.x, lane = tid & 63, w = tid >> 6;
  for (int tile = blockIdx.x; tile < ntiles; tile += gridDim.x) {
    int node = tile * 16 + w;
    float v0 = 0.f, v1 = 0.f, v2 = 0.f, v3 = 0.f;
    if (node < n) {
      const float4 adv = *(const float4*)&a_dst[(size_t)node * 4];
      int s0 = rowstart[node], s1 = rowstart[node + 1];
      float acc0 = 0, acc1 = 0, acc2 = 0, acc3 = 0;
      float S0 = 0, S1 = 0, S2 = 0, S3 = 0;
      for (int base = s0; base < s1; base += 64) {
        int cnt = min(64, s1 - base);
        bool act = (lane < cnt);
        int myidx = act ? colidx[base + lane] : 0;
        float w0 = 0, w1 = 0, w2 = 0, w3 = 0;
        if (act) {
          const float4 as = *(const float4*)&a_src[(size_t)myidx * 4];
          float e0 = as.x + adv.x; e0 = (e0 > 0.f) ? e0 : 0.2f * e0; w0 = __expf(e0);
          float e1 = as.y + adv.y; e1 = (e1 > 0.f) ? e1 : 0.2f * e1; w1 = __expf(e1);
          float e2 = as.z + adv.z; e2 = (e2 > 0.f) ? e2 : 0.2f * e2; w2 = __expf(e2);
          float e3 = as.w + adv.w; e3 = (e3 > 0.f) ? e3 : 0.2f * e3; w3 = __expf(e3);
        }
        S0 += wave_sum(w0); S1 += wave_sum(w1);
        S2 += wave_sum(w2); S3 += wave_sum(w3);
        wlds[w][lane] = make_float4(w0, w1, w2, w3);
        int k = 0;
        for (; k + 3 < cnt; k += 4) {
          int i0 = (ilanebcast(myidx, k) << 6) + lane;
          int i1 = (ilanebcast(myidx, k + 1) << 6) + lane;
          int i2 = (ilanebcast(myidx, k + 2) << 6) + lane;
          int i3 = (ilanebcast(myidx, k + 3) << 6) + lane;
          float4 wa = wlds[w][k];
          float4 wb = wlds[w][k + 1];
          float4 wc = wlds[w][k + 2];
          float4 wd = wlds[w][k + 3];
          float va = (float)x3[i0];
          float vb = (float)x3[i1];
          float vc = (float)x3[i2];
          float vd = (float)x3[i3];
          acc0 = fmaf(wa.x, va, acc0); acc1 = fmaf(wa.y, va, acc1);
          acc2 = fmaf(wa.z, va, acc2); acc3 = fmaf(wa.w, va, acc3);
          acc0 = fmaf(wb.x, vb, acc0); acc1 = fmaf(wb.y, vb, acc1);
          acc2 = fmaf(wb.z, vb, acc2); acc3 = fmaf(wb.w, vb, acc3);
          acc0 = fmaf(wc.x, vc, acc0); acc1 = fmaf(wc.y, vc, acc1);
          acc2 = fmaf(wc.z, vc, acc2); acc3 = fmaf(wc.w, vc, acc3);
          acc0 = fmaf(wd.x, vd, acc0); acc1 = fmaf(wd.y, vd, acc1);
          acc2 = fmaf(wd.z, vd, acc2); acc3 = fmaf(wd.w, vd, acc3);
        }
        for (; k < cnt; k++) {
          int i0 = (ilanebcast(myidx, k) << 6) + lane;
          float4 wa = wlds[w][k];
          float va = (float)x3[i0];
          acc0 = fmaf(wa.x, va, acc0); acc1 = fmaf(wa.y, va, acc1);
          acc2 = fmaf(wa.z, va, acc2); acc3 = fmaf(wa.w, va, acc3);
        }
      }
      v0 = acc0 * (0.25f / S0);
      v1 = acc1 * (0.25f / S1);
      v2 = acc2 * (0.25f / S2);
      v3 = acc3 * (0.25f / S3);
    }
    astage[w][lane] = v0;
    astage[w][64 + lane] = v1;
    astage[w][128 + lane] = v2;
    astage[w][192 + lane] = v3;
    __syncthreads();
    if (w < 4) {
      int m = lane & 15, q = lane >> 4, ct = w;
      float bv = bias[ct * 16 + m];
      f4 acc = (f4){0.f, 0.f, 0.f, 0.f};
#pragma unroll 2
      for (int kc = 0; kc < 8; kc++) {
        const float* ap = &astage[m][kc * 32 + q * 8];
        union { _Float16 u[8]; h8 v; } Uh, Ul;
#pragma unroll
        for (int j = 0; j < 8; j++) {
          float a = ap[j];
          _Float16 h = (_Float16)a;
          Uh.u[j] = h;
          Ul.u[j] = (_Float16)(a - (float)h);
        }
        size_t boff = ((size_t)(ct * 8 + kc) * 64 + lane) * 8;
        h8 bh = *(const h8*)(Bh + boff);
        h8 bl = *(const h8*)(Bl + boff);
        acc = __builtin_amdgcn_mfma_f32_16x16x32_f16(Uh.v, bh, acc, 0, 0, 0);
        acc = __builtin_amdgcn_mfma_f32_16x16x32_f16(Ul.v, bh, acc, 0, 0, 0);
        acc = __builtin_amdgcn_mfma_f32_16x16x32_f16(Uh.v, bl, acc, 0, 0, 0);
      }
#pragma unroll
      for (int r = 0; r < 4; r++) {
        int row = tile * 16 + q * 4 + r;
        if (row < n)
          out[(size_t)row * 64 + ct * 16 + m] = fmaxf(acc[r] + bv, 0.f);
      }
    }
    __syncthreads();
  }
}

// ---------------- fused pooling + MLP head (wave per graph) ----------------
__global__ __launch_bounds__(256) void k_pool_mlp(
    const float* __restrict__ x, const int* __restrict__ batch,
    const float* __restrict__ w1, const float* __restrict__ b1,
    const float* __restrict__ w2, const float* __restrict__ b2,
    float* __restrict__ out, int n, int B) {
  __shared__ float gls[4][64];
  int tid = threadIdx.x, lane = tid & 63, w = tid >> 6;
  int g = blockIdx.x * 4 + w;
  if (g >= B) return;
  int lo = 0, hi = n;
  while (lo < hi) { int mid = (lo + hi) >> 1; if (batch[mid] < g) lo = mid + 1; else hi = mid; }
  int s0 = lo;
  lo = 0; hi = n;
  while (lo < hi) { int mid = (lo + hi) >> 1; if (batch[mid] < g + 1) lo = mid + 1; else hi = mid; }
  int s1 = lo;
  float sum = 0.0f, mx = -INFINITY;
  for (int nd = s0; nd < s1; ++nd) {
    float v = x[(size_t)nd * 64 + lane];
    sum += v;
    mx = fmaxf(mx, v);
  }
  int cnt = s1 - s0;
  float mean = sum / fmaxf((float)cnt, 1.0f);
  float mp = (cnt > 0) ? mx : 0.0f;
  gls[w][lane] = mean + mp;
  float a = 0.0f;
  if (lane < 32) {
    a = b1[lane];
    for (int i = 0; i < 64; i++) a = fmaf(gls[w][i], w1[i * 32 + lane], a);
    a = fmaxf(a, 0.0f);
  }
  float p0 = (lane < 32) ? a * w2[lane * 2 + 0] : 0.0f;
  float p1 = (lane < 32) ? a * w2[lane * 2 + 1] : 0.0f;
  p0 = wave_sum(p0);
  p1 = wave_sum(p1);
  if (lane == 0) {
    out[g * 2 + 0] = b2[0] + p0;
    out[g * 2 + 1] = b2[1] + p1;
  }
}

// ---------------- launch ----------------
extern "C" void kernel_launch(void* const* d_in, const int* in_sizes, int n_in,
                              void* d_out, int out_size, void* d_ws, size_t ws_size,
                              hipStream_t stream) {
  const float* x     = (const float*)d_in[0];
  const int*   ei    = (const int*)d_in[1];
  const int*   batch = (const int*)d_in[2];
  const float* w0 = (const float*)d_in[3];  const float* b0 = (const float*)d_in[4];
  const float* w1 = (const float*)d_in[5];  const float* b1 = (const float*)d_in[6];
  const float* w2 = (const float*)d_in[7];  const float* b2 = (const float*)d_in[8];
  const float* gat_w = (const float*)d_in[9];
  const float* att_s = (const float*)d_in[10];
  const float* att_d = (const float*)d_in[11];
  const float* gat_b = (const float*)d_in[12];
  const float* l1w = (const float*)d_in[13]; const float* l1b = (const float*)d_in[14];
  const float* l2w = (const float*)d_in[15]; const float* l2b = (const float*)d_in[16];

  const int N = in_sizes[0] / 128;
  const int E = in_sizes[1] / 2;
  const int B = out_size / 2;
  const int NT = (N + 15) / 16;
  const int NBUK = (N + BRANGE - 1) / BRANGE;
  const int PGB = 512;  // persistent grid for agg kernels (2/CU)

  char* ws = (char*)d_ws;
  size_t off = 0;
  auto alloc = [&](size_t bytes) -> void* {
    void* p = ws + off;
    off = (off + bytes + 255) & ~(size_t)255;
    return p;
  };
  int*       bhistT   = (int*)alloc((size_t)NBUK * NB_E * 4);
  int*       edgebase = (int*)alloc((size_t)NBUK * 4);
  int*       bcnt     = (int*)alloc((size_t)NBUK * 4);
  int*       bedges   = (int*)alloc((size_t)E * 4);
  int*       rowstart = (int*)alloc((size_t)(N + 1) * 4);
  int*       colidx   = (int*)alloc((size_t)(E + N) * 4);
  float*     dinv     = (float*)alloc((size_t)N * 4);
  _Float16*  hbuf     = (_Float16*)alloc((size_t)N * 64 * 2);
  _Float16*  hbuf2    = (_Float16*)alloc((size_t)N * 64 * 2);
  _Float16*  xg       = (_Float16*)alloc((size_t)N * 64 * 2);
  float*     gatout   = (float*)alloc((size_t)N * 64 * 4);
  float*     a_src    = (float*)alloc((size_t)N * 4 * 4);
  float*     a_dst    = (float*)alloc((size_t)N * 4 * 4);
  ushort_t*  B0h      = (ushort_t*)alloc(4 * 4 * 64 * 8 * 2);
  ushort_t*  B0l      = (ushort_t*)alloc(4 * 4 * 64 * 8 * 2);
  _Float16*  Bw1h     = (_Float16*)alloc(8 * 64 * 8 * 2);
  _Float16*  Bw1l     = (_Float16*)alloc(8 * 64 * 8 * 2);
  _Float16*  Bw2h     = (_Float16*)alloc(8 * 64 * 8 * 2);
  _Float16*  Bw2l     = (_Float16*)alloc(8 * 64 * 8 * 2);
  _Float16*  Bq       = (_Float16*)alloc(2 * 64 * 8 * 2);
  _Float16*  Bgh      = (_Float16*)alloc(4 * 8 * 64 * 8 * 2);
  _Float16*  Bgl      = (_Float16*)alloc(4 * 8 * 64 * 8 * 2);
  (void)ws_size; (void)n_in;

  // CSR build
  k_ehist<<<NB_E, 256, 0, stream>>>(ei + E, bhistT, E, NBUK);
  k_btot<<<NBUK, 256, 0, stream>>>(bhistT, bcnt, NB_E);
  k_bscan<<<1, 512, 0, stream>>>(bcnt, edgebase, NBUK, rowstart, N, E);
  k_bbase<<<NBUK, 256, 0, stream>>>(bhistT, edgebase, NB_E);
  k_ebucket<<<NB_E, 256, 0, stream>>>(ei, ei + E, bhistT, bedges, E, NBUK);
  k_ebsort<<<NBUK, 256, 0, stream>>>(bedges, edgebase, bcnt, colidx, rowstart, dinv, N);
  // weight prep (fused)
  k_qprep<<<1, 256, 0, stream>>>(gat_w, att_s, att_d, Bq);
  k_wswz_all<<<16, 256, 0, stream>>>(w0, B0h, B0l, w1, Bw1h, Bw1l,
                                     w2, Bw2h, Bw2l, gat_w, Bgh, Bgl);

  // K1: h0' = f16(dinv * (x @ W0))
  k_gemm0_mfma<<<1024, 256, 0, stream>>>(x, B0h, B0l, dinv, hbuf, N, NT);
  // K2: x1 = relu(dinv*agg(h0')+b0); h1' = f16(dinv*(x1@W1))
  k_agg_gemm_mfma<<<PGB, 1024, 0, stream>>>(hbuf, dinv, rowstart, colidx, b0,
                                            Bw1h, Bw1l, hbuf2, N, NT);
  // K3
  k_agg_gemm_mfma<<<PGB, 1024, 0, stream>>>(hbuf2, dinv, rowstart, colidx, b1,
                                            Bw2h, Bw2l, hbuf, N, NT);
  // K4: x3 (f16) + attention logits via MFMA
  k_agg_gatpre_mfma<<<PGB, 1024, 0, stream>>>(hbuf, dinv, rowstart, colidx, b2,
                                              Bq, xg, a_src, a_dst, N, NT);
  // K5 fused: softmax-aggregate + 256->64 projection + bias + relu
  k_gat_fused<<<PGB, 1024, 0, stream>>>(xg, a_src, a_dst, rowstart, colidx,
                                        Bgh, Bgl, gat_b, gatout, N, NT);
  // fused pooling + MLP head
  k_pool_mlp<<<(B + 3) / 4, 256, 0, stream>>>(gatout, batch, l1w, l1b, l2w, l2b,
                                              (float*)d_out, N, B);
}

// Round 18
// 341.404 us; speedup vs baseline: 1.0781x; 1.0781x over previous
//
#include <hip/hip_runtime.h>
#include <math.h>

typedef short bf8 __attribute__((ext_vector_type(8)));     // 8 bf16 (4 VGPRs)
typedef _Float16 h8 __attribute__((ext_vector_type(8)));   // 8 f16  (4 VGPRs)
typedef float f4 __attribute__((ext_vector_type(4)));
typedef unsigned short ushort_t;

#define BRANGE 128  // nodes per bucket (dst>>7)
#define NB_E 256    // blocks for edge hist/scatter

// ---------------- helpers ----------------
__device__ __forceinline__ int ilanebcast(int v, int l) {
  return __builtin_amdgcn_readlane(v, l);
}

__device__ __forceinline__ float wave_sum(float v) {
#pragma unroll
  for (int off = 32; off > 0; off >>= 1) v += __shfl_xor(v, off, 64);
  return v;
}

__device__ __forceinline__ ushort_t f2bf(float x) {  // RNE fp32->bf16 bits
  unsigned int u = __float_as_uint(x);
  return (ushort_t)((u + 0x7fffu + ((u >> 16) & 1u)) >> 16);
}
__device__ __forceinline__ float b2f(ushort_t h) {
  return __uint_as_float(((unsigned int)h) << 16);
}

// ================= contention-free bucketed CSR build =================
__global__ __launch_bounds__(256) void k_ehist(const int* __restrict__ dst,
                                               int* __restrict__ bhistT, int E, int nbuk) {
  __shared__ int h[512];
  int b = blockIdx.x, tid = threadIdx.x;
  for (int i = tid; i < nbuk; i += 256) h[i] = 0;
  __syncthreads();
  int chunk = (E + gridDim.x - 1) / gridDim.x;
  int e0 = b * chunk, e1 = min(E, e0 + chunk);
  for (int e = e0 + tid; e < e1; e += 256) atomicAdd(&h[dst[e] >> 7], 1);
  __syncthreads();
  for (int i = tid; i < nbuk; i += 256) bhistT[i * NB_E + b] = h[i];
}

__global__ __launch_bounds__(256) void k_btot(const int* __restrict__ bhistT,
                                              int* __restrict__ bcnt, int nb) {
  __shared__ int sm[256];
  int b = blockIdx.x, tid = threadIdx.x;
  sm[tid] = (tid < nb) ? bhistT[b * NB_E + tid] : 0;
  __syncthreads();
  for (int off = 128; off > 0; off >>= 1) {
    if (tid < off) sm[tid] += sm[tid + off];
    __syncthreads();
  }
  if (tid == 0) bcnt[b] = sm[0];
}

__global__ __launch_bounds__(512) void k_bscan(
    const int* __restrict__ bcnt, int* __restrict__ edgebase, int nbuk,
    int* __restrict__ rowstart, int n, int E) {
  __shared__ int smem[512];
  int t = threadIdx.x;
  int v = (t < nbuk) ? bcnt[t] : 0;
  smem[t] = v;
  __syncthreads();
  for (int off = 1; off < 512; off <<= 1) {
    int u = (t >= off) ? smem[t - off] : 0;
    __syncthreads();
    smem[t] += u;
    __syncthreads();
  }
  if (t < nbuk) edgebase[t] = smem[t] - v;
  if (t == 0) rowstart[n] = E + n;
}

__global__ __launch_bounds__(256) void k_bbase(int* __restrict__ bhistT,
                                               const int* __restrict__ edgebase,
                                               int nb) {
  __shared__ int sm[256];
  int b = blockIdx.x, tid = threadIdx.x;
  int v = (tid < nb) ? bhistT[b * NB_E + tid] : 0;
  sm[tid] = v;
  __syncthreads();
  for (int off = 1; off < 256; off <<= 1) {
    int u = (tid >= off) ? sm[tid - off] : 0;
    __syncthreads();
    sm[tid] += u;
    __syncthreads();
  }
  if (tid < nb) bhistT[b * NB_E + tid] = edgebase[b] + sm[tid] - v;
}

__global__ __launch_bounds__(256) void k_ebucket(
    const int* __restrict__ es, const int* __restrict__ ed,
    const int* __restrict__ bhistT, int* __restrict__ bedges, int E, int nbuk) {
  __shared__ int cur[512];
  int b = blockIdx.x, tid = threadIdx.x;
  for (int i = tid; i < nbuk; i += 256) cur[i] = bhistT[i * NB_E + b];
  __syncthreads();
  int chunk = (E + gridDim.x - 1) / gridDim.x;
  int e0 = b * chunk, e1 = min(E, e0 + chunk);
  for (int e = e0 + tid; e < e1; e += 256) {
    int s = es[e], d = ed[e];
    int pos = atomicAdd(&cur[d >> 7], 1);
    bedges[pos] = (s << 7) | (d & 127);
  }
}

__global__ __launch_bounds__(256) void k_ebsort(
    const int* __restrict__ bedges, const int* __restrict__ edgebase,
    const int* __restrict__ bcnt, int* __restrict__ colidx,
    int* __restrict__ rowstart, float* __restrict__ dinv, int n) {
  __shared__ int h[128];
  __shared__ int c[128];
  int b = blockIdx.x, tid = threadIdx.x;
  int nodes0 = b * BRANGE;
  int nnode = min(BRANGE, n - nodes0);
  int ebase = edgebase[b], ecnt = bcnt[b];
  int colbase = ebase + nodes0;
  if (tid < 128) h[tid] = (tid < nnode) ? 1 : 0;  // self-loop
  __syncthreads();
  for (int k = ebase + tid; k < ebase + ecnt; k += 256)
    atomicAdd(&h[bedges[k] & 127], 1);
  __syncthreads();
  int own = (tid < 128) ? h[tid] : 0;
  for (int off = 1; off < 128; off <<= 1) {
    int t = (tid >= off && tid < 128) ? h[tid - off] : 0;
    __syncthreads();
    if (tid < 128) h[tid] += t;
    __syncthreads();
  }
  if (tid < nnode) {
    int excl = h[tid] - own;
    int node = nodes0 + tid;
    rowstart[node] = colbase + excl;
    dinv[node] = 1.0f / sqrtf((float)own);
    colidx[colbase + excl] = node;  // self-loop first
    c[tid] = excl + 1;
  }
  __syncthreads();
  for (int k = ebase + tid; k < ebase + ecnt; k += 256) {
    int p = bedges[k];
    int pos = atomicAdd(&c[p & 127], 1);
    colidx[colbase + pos] = p >> 7;
  }
}

// ---------------- fused weight swizzles (one kernel, 16 blocks) -------------
__global__ __launch_bounds__(256) void k_wswz_all(
    const float* __restrict__ W0, ushort_t* __restrict__ B0h, ushort_t* __restrict__ B0l,
    const float* __restrict__ W1, _Float16* __restrict__ Bw1h, _Float16* __restrict__ Bw1l,
    const float* __restrict__ W2, _Float16* __restrict__ Bw2h, _Float16* __restrict__ Bw2l,
    const float* __restrict__ Wg, _Float16* __restrict__ Bgh, _Float16* __restrict__ Bgl) {
  int bid = blockIdx.x, tid = threadIdx.x;
  if (bid < 4) {
    int e = bid * 256 + tid;
    int lane = e & 63, kc = (e >> 6) & 3, ct = e >> 8;
    int k0 = kc * 32 + (lane >> 4) * 8;
    int col = ct * 16 + (lane & 15);
#pragma unroll
    for (int j = 0; j < 8; j++) {
      float w = W0[(k0 + j) * 64 + col];
      ushort_t h = f2bf(w);
      B0h[(size_t)e * 8 + j] = h;
      B0l[(size_t)e * 8 + j] = f2bf(w - b2f(h));
    }
  } else if (bid < 8) {
    const float* W = (bid < 6) ? W1 : W2;
    _Float16* Bh = (bid < 6) ? Bw1h : Bw2h;
    _Float16* Bl = (bid < 6) ? Bw1l : Bw2l;
    int e = ((bid - 4) & 1) * 256 + tid;
    int lane = e & 63, kc = (e >> 6) & 1, ct = e >> 7;
    int k0 = kc * 32 + (lane >> 4) * 8;
    int col = ct * 16 + (lane & 15);
#pragma unroll
    for (int j = 0; j < 8; j++) {
      float w = W[(k0 + j) * 64 + col];
      _Float16 h = (_Float16)w;
      Bh[(size_t)e * 8 + j] = h;
      Bl[(size_t)e * 8 + j] = (_Float16)(w - (float)h);
    }
  } else {
    int e = (bid - 8) * 256 + tid;
    int lane = e & 63, kc = (e >> 6) & 7, ct = e >> 9;
    int k0 = kc * 32 + (lane >> 4) * 8;
    int col = ct * 16 + (lane & 15);
#pragma unroll
    for (int j = 0; j < 8; j++) {
      int k = k0 + j;
      float w = Wg[(k & 63) * 256 + (k >> 6) * 64 + col];
      _Float16 h = (_Float16)w;
      Bgh[(size_t)e * 8 + j] = h;
      Bgl[(size_t)e * 8 + j] = (_Float16)(w - (float)h);
    }
  }
}

// ---------------- fused q prep ----------------
__global__ __launch_bounds__(256) void k_qprep(
    const float* __restrict__ W, const float* __restrict__ att_s,
    const float* __restrict__ att_d, _Float16* __restrict__ Bq) {
  __shared__ float qs[256], qd[256];
  int t = threadIdx.x;
  int h = t >> 6, k = t & 63;
  float ss = 0.0f, sd = 0.0f;
  for (int c = 0; c < 64; c++) {
    float w = W[k * 256 + h * 64 + c];
    ss = fmaf(w, att_s[h * 64 + c], ss);
    sd = fmaf(w, att_d[h * 64 + c], sd);
  }
  qs[h * 64 + k] = ss;
  qd[h * 64 + k] = sd;
  __syncthreads();
  if (t < 128) {
    int lane = t & 63, kc = t >> 6;
    int k0 = kc * 32 + (lane >> 4) * 8;
    int col = lane & 15;
#pragma unroll
    for (int j = 0; j < 8; j++) {
      int kk = k0 + j;
      float v = (col < 4) ? qs[col * 64 + kk]
                          : ((col < 8) ? qd[(col - 4) * 64 + kk] : 0.0f);
      Bq[(size_t)t * 8 + j] = (_Float16)v;
    }
  }
}

// ---------------- K1: H0'[N,64] = f16(dinv[n] * (X[N,128] @ W0)) via MFMA --
__global__ __launch_bounds__(256) void k_gemm0_mfma(
    const float* __restrict__ X, const ushort_t* __restrict__ Bh,
    const ushort_t* __restrict__ Bl, const float* __restrict__ dinv,
    _Float16* __restrict__ H, int n, int ntiles) {
  int tid = threadIdx.x, lane = tid & 63, wave = tid >> 6;
  int m = lane & 15, q = lane >> 4;
  for (int tile = blockIdx.x * 4 + wave; tile < ntiles; tile += gridDim.x * 4) {
    int ra = tile * 16 + m;
    if (ra >= n) ra = n - 1;
    const float* xrow = X + (size_t)ra * 128;
    f4 acc[4];
#pragma unroll
    for (int ct = 0; ct < 4; ct++) acc[ct] = (f4){0.f, 0.f, 0.f, 0.f};
#pragma unroll 2
    for (int kc = 0; kc < 4; kc++) {
      int ko = kc * 32 + q * 8;
      float4 xa = *(const float4*)(xrow + ko);
      float4 xb = *(const float4*)(xrow + ko + 4);
      float f[8] = {xa.x, xa.y, xa.z, xa.w, xb.x, xb.y, xb.z, xb.w};
      union { ushort_t u[8]; bf8 v; } Uh, Ul;
#pragma unroll
      for (int j = 0; j < 8; j++) {
        ushort_t h = f2bf(f[j]);
        Uh.u[j] = h;
        Ul.u[j] = f2bf(f[j] - b2f(h));
      }
#pragma unroll
      for (int ct = 0; ct < 4; ct++) {
        size_t boff = ((size_t)(ct * 4 + kc) * 64 + lane) * 8;
        bf8 bh = *(const bf8*)(Bh + boff);
        bf8 bl = *(const bf8*)(Bl + boff);
        acc[ct] = __builtin_amdgcn_mfma_f32_16x16x32_bf16(Uh.v, bh, acc[ct], 0, 0, 0);
        acc[ct] = __builtin_amdgcn_mfma_f32_16x16x32_bf16(Ul.v, bh, acc[ct], 0, 0, 0);
        acc[ct] = __builtin_amdgcn_mfma_f32_16x16x32_bf16(Uh.v, bl, acc[ct], 0, 0, 0);
      }
    }
#pragma unroll
    for (int r = 0; r < 4; r++) {
      int row = tile * 16 + q * 4 + r;
      if (row < n) {
        float dv = dinv[row];
#pragma unroll
        for (int ct = 0; ct < 4; ct++)
          H[(size_t)row * 64 + ct * 16 + m] = (_Float16)(acc[ct][r] * dv);
      }
    }
  }
}

// ---------------- gather core (f16 rows, 32-bit offsets, unroll 8) ----------
__device__ __forceinline__ float gather_sum(const _Float16* __restrict__ h_in,
                                            const int* __restrict__ colidx,
                                            int s0, int s1, int lane) {
  float acc = 0.0f, accB = 0.0f;
  for (int base = s0; base < s1; base += 64) {
    int cnt = min(64, s1 - base);
    int myidx = (lane < cnt) ? colidx[base + lane] : 0;
    int k = 0;
    for (; k + 7 < cnt; k += 8) {
      int i0 = (ilanebcast(myidx, k) << 6) + lane;
      int i1 = (ilanebcast(myidx, k + 1) << 6) + lane;
      int i2 = (ilanebcast(myidx, k + 2) << 6) + lane;
      int i3 = (ilanebcast(myidx, k + 3) << 6) + lane;
      int i4 = (ilanebcast(myidx, k + 4) << 6) + lane;
      int i5 = (ilanebcast(myidx, k + 5) << 6) + lane;
      int i6 = (ilanebcast(myidx, k + 6) << 6) + lane;
      int i7 = (ilanebcast(myidx, k + 7) << 6) + lane;
      float v0 = (float)h_in[i0];
      float v1 = (float)h_in[i1];
      float v2 = (float)h_in[i2];
      float v3 = (float)h_in[i3];
      float v4 = (float)h_in[i4];
      float v5 = (float)h_in[i5];
      float v6 = (float)h_in[i6];
      float v7 = (float)h_in[i7];
      acc += v0; accB += v1; acc += v2; accB += v3;
      acc += v4; accB += v5; acc += v6; accB += v7;
    }
    for (; k + 3 < cnt; k += 4) {
      int i0 = (ilanebcast(myidx, k) << 6) + lane;
      int i1 = (ilanebcast(myidx, k + 1) << 6) + lane;
      int i2 = (ilanebcast(myidx, k + 2) << 6) + lane;
      int i3 = (ilanebcast(myidx, k + 3) << 6) + lane;
      acc += (float)h_in[i0]; accB += (float)h_in[i1];
      acc += (float)h_in[i2]; accB += (float)h_in[i3];
    }
    for (; k < cnt; k++) {
      int i0 = (ilanebcast(myidx, k) << 6) + lane;
      acc += (float)h_in[i0];
    }
  }
  return acc + accB;
}

// ---------------- K2/K3: 16-wave block: parallel gathers + MFMA GEMV -------
__global__ __launch_bounds__(1024) void k_agg_gemm_mfma(
    const _Float16* __restrict__ h_in, const float* __restrict__ dinv,
    const int* __restrict__ rowstart, const int* __restrict__ colidx,
    const float* __restrict__ bias, const _Float16* __restrict__ Bh,
    const _Float16* __restrict__ Bl, _Float16* __restrict__ h_out, int n) {
  __shared__ __align__(16) _Float16 xstage[16][72];
  int tid = threadIdx.x, lane = tid & 63, w = tid >> 6;
  int tile = blockIdx.x;
  int node = tile * 16 + w;
  float xv = 0.0f;
  if (node < n) {
    int s0 = rowstart[node], s1 = rowstart[node + 1];
    float a = gather_sum(h_in, colidx, s0, s1, lane);
    xv = fmaxf(fmaf(dinv[node], a, bias[lane]), 0.0f);
  }
  xstage[w][lane] = (_Float16)xv;
  __syncthreads();
  if (w < 4) {
    int m = lane & 15, q = lane >> 4, ct = w;
    h8 af0 = *(const h8*)&xstage[m][q * 8];
    h8 af1 = *(const h8*)&xstage[m][32 + q * 8];
    size_t o0 = ((size_t)(ct * 2 + 0) * 64 + lane) * 8;
    size_t o1 = ((size_t)(ct * 2 + 1) * 64 + lane) * 8;
    h8 bh0 = *(const h8*)(Bh + o0);
    h8 bh1 = *(const h8*)(Bh + o1);
    h8 bl0 = *(const h8*)(Bl + o0);
    h8 bl1 = *(const h8*)(Bl + o1);
    f4 acc = (f4){0.f, 0.f, 0.f, 0.f};
    acc = __builtin_amdgcn_mfma_f32_16x16x32_f16(af0, bh0, acc, 0, 0, 0);
    acc = __builtin_amdgcn_mfma_f32_16x16x32_f16(af1, bh1, acc, 0, 0, 0);
    acc = __builtin_amdgcn_mfma_f32_16x16x32_f16(af0, bl0, acc, 0, 0, 0);
    acc = __builtin_amdgcn_mfma_f32_16x16x32_f16(af1, bl1, acc, 0, 0, 0);
#pragma unroll
    for (int r = 0; r < 4; r++) {
      int n2 = tile * 16 + q * 4 + r;
      if (n2 < n)
        h_out[(size_t)n2 * 64 + ct * 16 + m] = (_Float16)(acc[r] * dinv[n2]);
    }
  }
}

// ---------------- K4: 16-wave block: gathers -> x3 + logits via MFMA -------
__global__ __launch_bounds__(1024) void k_agg_gatpre_mfma(
    const _Float16* __restrict__ h_in, const float* __restrict__ dinv,
    const int* __restrict__ rowstart, const int* __restrict__ colidx,
    const float* __restrict__ bias, const _Float16* __restrict__ Bq,
    _Float16* __restrict__ x3, float* __restrict__ a_src, float* __restrict__ a_dst,
    int n) {
  __shared__ __align__(16) _Float16 xstage[16][72];
  int tid = threadIdx.x, lane = tid & 63, w = tid >> 6;
  int tile = blockIdx.x;
  int node = tile * 16 + w;
  float xv = 0.0f;
  if (node < n) {
    int s0 = rowstart[node], s1 = rowstart[node + 1];
    float a = gather_sum(h_in, colidx, s0, s1, lane);
    xv = fmaxf(fmaf(dinv[node], a, bias[lane]), 0.0f);
    x3[(node << 6) + lane] = (_Float16)xv;
  }
  xstage[w][lane] = (_Float16)xv;
  __syncthreads();
  if (w == 0) {
    int m = lane & 15, q = lane >> 4;
    h8 af0 = *(const h8*)&xstage[m][q * 8];
    h8 af1 = *(const h8*)&xstage[m][32 + q * 8];
    h8 bq0 = *(const h8*)(Bq + (size_t)lane * 8);
    h8 bq1 = *(const h8*)(Bq + (size_t)(64 + lane) * 8);
    f4 accL = (f4){0.f, 0.f, 0.f, 0.f};
    accL = __builtin_amdgcn_mfma_f32_16x16x32_f16(af0, bq0, accL, 0, 0, 0);
    accL = __builtin_amdgcn_mfma_f32_16x16x32_f16(af1, bq1, accL, 0, 0, 0);
#pragma unroll
    for (int r = 0; r < 4; r++) {
      int n2 = tile * 16 + q * 4 + r;
      if (n2 < n) {
        if (m < 4) a_src[(size_t)n2 * 4 + m] = accL[r];
        else if (m < 8) a_dst[(size_t)n2 * 4 + (m - 4)] = accL[r];
      }
    }
  }
}

// ---------------- K5 fused: GAT softmax-aggregate + projection -------------
__global__ __launch_bounds__(1024) void k_gat_fused(
    const _Float16* __restrict__ x3, const float* __restrict__ a_src,
    const float* __restrict__ a_dst, const int* __restrict__ rowstart,
    const int* __restrict__ colidx, const _Float16* __restrict__ Bh,
    const _Float16* __restrict__ Bl, const float* __restrict__ bias,
    float* __restrict__ out, int n) {
  __shared__ __align__(16) float4 wlds[16][64];   // 16 KB
  __shared__ float astage[16][261];               // 16.7 KB
  int tid = threadIdx.x, lane = tid & 63, w = tid >> 6;
  int tile = blockIdx.x;
  int node = tile * 16 + w;
  float v0 = 0.f, v1 = 0.f, v2 = 0.f, v3 = 0.f;
  if (node < n) {
    const float4 adv = *(const float4*)&a_dst[(size_t)node * 4];
    int s0 = rowstart[node], s1 = rowstart[node + 1];
    float acc0 = 0, acc1 = 0, acc2 = 0, acc3 = 0;
    float S0 = 0, S1 = 0, S2 = 0, S3 = 0;
    for (int base = s0; base < s1; base += 64) {
      int cnt = min(64, s1 - base);
      bool act = (lane < cnt);
      int myidx = act ? colidx[base + lane] : 0;
      float w0 = 0, w1 = 0, w2 = 0, w3 = 0;
      if (act) {
        const float4 as = *(const float4*)&a_src[(size_t)myidx * 4];
        float e0 = as.x + adv.x; e0 = (e0 > 0.f) ? e0 : 0.2f * e0; w0 = __expf(e0);
        float e1 = as.y + adv.y; e1 = (e1 > 0.f) ? e1 : 0.2f * e1; w1 = __expf(e1);
        float e2 = as.z + adv.z; e2 = (e2 > 0.f) ? e2 : 0.2f * e2; w2 = __expf(e2);
        float e3 = as.w + adv.w; e3 = (e3 > 0.f) ? e3 : 0.2f * e3; w3 = __expf(e3);
      }
      S0 += wave_sum(w0); S1 += wave_sum(w1);
      S2 += wave_sum(w2); S3 += wave_sum(w3);
      wlds[w][lane] = make_float4(w0, w1, w2, w3);
      int k = 0;
      for (; k + 3 < cnt; k += 4) {
        int i0 = (ilanebcast(myidx, k) << 6) + lane;
        int i1 = (ilanebcast(myidx, k + 1) << 6) + lane;
        int i2 = (ilanebcast(myidx, k + 2) << 6) + lane;
        int i3 = (ilanebcast(myidx, k + 3) << 6) + lane;
        float4 wa = wlds[w][k];
        float4 wb = wlds[w][k + 1];
        float4 wc = wlds[w][k + 2];
        float4 wd = wlds[w][k + 3];
        float va = (float)x3[i0];
        float vb = (float)x3[i1];
        float vc = (float)x3[i2];
        float vd = (float)x3[i3];
        acc0 = fmaf(wa.x, va, acc0); acc1 = fmaf(wa.y, va, acc1);
        acc2 = fmaf(wa.z, va, acc2); acc3 = fmaf(wa.w, va, acc3);
        acc0 = fmaf(wb.x, vb, acc0); acc1 = fmaf(wb.y, vb, acc1);
        acc2 = fmaf(wb.z, vb, acc2); acc3 = fmaf(wb.w, vb, acc3);
        acc0 = fmaf(wc.x, vc, acc0); acc1 = fmaf(wc.y, vc, acc1);
        acc2 = fmaf(wc.z, vc, acc2); acc3 = fmaf(wc.w, vc, acc3);
        acc0 = fmaf(wd.x, vd, acc0); acc1 = fmaf(wd.y, vd, acc1);
        acc2 = fmaf(wd.z, vd, acc2); acc3 = fmaf(wd.w, vd, acc3);
      }
      for (; k < cnt; k++) {
        int i0 = (ilanebcast(myidx, k) << 6) + lane;
        float4 wa = wlds[w][k];
        float va = (float)x3[i0];
        acc0 = fmaf(wa.x, va, acc0); acc1 = fmaf(wa.y, va, acc1);
        acc2 = fmaf(wa.z, va, acc2); acc3 = fmaf(wa.w, va, acc3);
      }
    }
    v0 = acc0 * (0.25f / S0);
    v1 = acc1 * (0.25f / S1);
    v2 = acc2 * (0.25f / S2);
    v3 = acc3 * (0.25f / S3);
  }
  astage[w][lane] = v0;
  astage[w][64 + lane] = v1;
  astage[w][128 + lane] = v2;
  astage[w][192 + lane] = v3;
  __syncthreads();
  if (w < 4) {
    int m = lane & 15, q = lane >> 4, ct = w;
    float bv = bias[ct * 16 + m];
    f4 acc = (f4){0.f, 0.f, 0.f, 0.f};
#pragma unroll 2
    for (int kc = 0; kc < 8; kc++) {
      const float* ap = &astage[m][kc * 32 + q * 8];
      union { _Float16 u[8]; h8 v; } Uh, Ul;
#pragma unroll
      for (int j = 0; j < 8; j++) {
        float a = ap[j];
        _Float16 h = (_Float16)a;
        Uh.u[j] = h;
        Ul.u[j] = (_Float16)(a - (float)h);
      }
      size_t boff = ((size_t)(ct * 8 + kc) * 64 + lane) * 8;
      h8 bh = *(const h8*)(Bh + boff);
      h8 bl = *(const h8*)(Bl + boff);
      acc = __builtin_amdgcn_mfma_f32_16x16x32_f16(Uh.v, bh, acc, 0, 0, 0);
      acc = __builtin_amdgcn_mfma_f32_16x16x32_f16(Ul.v, bh, acc, 0, 0, 0);
      acc = __builtin_amdgcn_mfma_f32_16x16x32_f16(Uh.v, bl, acc, 0, 0, 0);
    }
#pragma unroll
    for (int r = 0; r < 4; r++) {
      int row = tile * 16 + q * 4 + r;
      if (row < n)
        out[(size_t)row * 64 + ct * 16 + m] = fmaxf(acc[r] + bv, 0.f);
    }
  }
}

// ---------------- fused pooling + MLP head (wave per graph) ----------------
__global__ __launch_bounds__(256) void k_pool_mlp(
    const float* __restrict__ x, const int* __restrict__ batch,
    const float* __restrict__ w1, const float* __restrict__ b1,
    const float* __restrict__ w2, const float* __restrict__ b2,
    float* __restrict__ out, int n, int B) {
  __shared__ float gls[4][64];
  int tid = threadIdx.x, lane = tid & 63, w = tid >> 6;
  int g = blockIdx.x * 4 + w;
  if (g >= B) return;
  int lo = 0, hi = n;
  while (lo < hi) { int mid = (lo + hi) >> 1; if (batch[mid] < g) lo = mid + 1; else hi = mid; }
  int s0 = lo;
  lo = 0; hi = n;
  while (lo < hi) { int mid = (lo + hi) >> 1; if (batch[mid] < g + 1) lo = mid + 1; else hi = mid; }
  int s1 = lo;
  float sum = 0.0f, mx = -INFINITY;
  for (int nd = s0; nd < s1; ++nd) {
    float v = x[(size_t)nd * 64 + lane];
    sum += v;
    mx = fmaxf(mx, v);
  }
  int cnt = s1 - s0;
  float mean = sum / fmaxf((float)cnt, 1.0f);
  float mp = (cnt > 0) ? mx : 0.0f;
  gls[w][lane] = mean + mp;
  float a = 0.0f;
  if (lane < 32) {
    a = b1[lane];
    for (int i = 0; i < 64; i++) a = fmaf(gls[w][i], w1[i * 32 + lane], a);
    a = fmaxf(a, 0.0f);
  }
  float p0 = (lane < 32) ? a * w2[lane * 2 + 0] : 0.0f;
  float p1 = (lane < 32) ? a * w2[lane * 2 + 1] : 0.0f;
  p0 = wave_sum(p0);
  p1 = wave_sum(p1);
  if (lane == 0) {
    out[g * 2 + 0] = b2[0] + p0;
    out[g * 2 + 1] = b2[1] + p1;
  }
}

// ---------------- launch ----------------
extern "C" void kernel_launch(void* const* d_in, const int* in_sizes, int n_in,
                              void* d_out, int out_size, void* d_ws, size_t ws_size,
                              hipStream_t stream) {
  const float* x     = (const float*)d_in[0];
  const int*   ei    = (const int*)d_in[1];
  const int*   batch = (const int*)d_in[2];
  const float* w0 = (const float*)d_in[3];  const float* b0 = (const float*)d_in[4];
  const float* w1 = (const float*)d_in[5];  const float* b1 = (const float*)d_in[6];
  const float* w2 = (const float*)d_in[7];  const float* b2 = (const float*)d_in[8];
  const float* gat_w = (const float*)d_in[9];
  const float* att_s = (const float*)d_in[10];
  const float* att_d = (const float*)d_in[11];
  const float* gat_b = (const float*)d_in[12];
  const float* l1w = (const float*)d_in[13]; const float* l1b = (const float*)d_in[14];
  const float* l2w = (const float*)d_in[15]; const float* l2b = (const float*)d_in[16];

  const int N = in_sizes[0] / 128;
  const int E = in_sizes[1] / 2;
  const int B = out_size / 2;
  const int NT = (N + 15) / 16;
  const int NBUK = (N + BRANGE - 1) / BRANGE;

  char* ws = (char*)d_ws;
  size_t off = 0;
  auto alloc = [&](size_t bytes) -> void* {
    void* p = ws + off;
    off = (off + bytes + 255) & ~(size_t)255;
    return p;
  };
  int*       bhistT   = (int*)alloc((size_t)NBUK * NB_E * 4);
  int*       edgebase = (int*)alloc((size_t)NBUK * 4);
  int*       bcnt     = (int*)alloc((size_t)NBUK * 4);
  int*       bedges   = (int*)alloc((size_t)E * 4);
  int*       rowstart = (int*)alloc((size_t)(N + 1) * 4);
  int*       colidx   = (int*)alloc((size_t)(E + N) * 4);
  float*     dinv     = (float*)alloc((size_t)N * 4);
  _Float16*  hbuf     = (_Float16*)alloc((size_t)N * 64 * 2);
  _Float16*  hbuf2    = (_Float16*)alloc((size_t)N * 64 * 2);
  _Float16*  xg       = (_Float16*)alloc((size_t)N * 64 * 2);
  float*     gatout   = (float*)alloc((size_t)N * 64 * 4);
  float*     a_src    = (float*)alloc((size_t)N * 4 * 4);
  float*     a_dst    = (float*)alloc((size_t)N * 4 * 4);
  ushort_t*  B0h      = (ushort_t*)alloc(4 * 4 * 64 * 8 * 2);
  ushort_t*  B0l      = (ushort_t*)alloc(4 * 4 * 64 * 8 * 2);
  _Float16*  Bw1h     = (_Float16*)alloc(8 * 64 * 8 * 2);
  _Float16*  Bw1l     = (_Float16*)alloc(8 * 64 * 8 * 2);
  _Float16*  Bw2h     = (_Float16*)alloc(8 * 64 * 8 * 2);
  _Float16*  Bw2l     = (_Float16*)alloc(8 * 64 * 8 * 2);
  _Float16*  Bq       = (_Float16*)alloc(2 * 64 * 8 * 2);
  _Float16*  Bgh      = (_Float16*)alloc(4 * 8 * 64 * 8 * 2);
  _Float16*  Bgl      = (_Float16*)alloc(4 * 8 * 64 * 8 * 2);
  (void)ws_size; (void)n_in;

  // CSR build
  k_ehist<<<NB_E, 256, 0, stream>>>(ei + E, bhistT, E, NBUK);
  k_btot<<<NBUK, 256, 0, stream>>>(bhistT, bcnt, NB_E);
  k_bscan<<<1, 512, 0, stream>>>(bcnt, edgebase, NBUK, rowstart, N, E);
  k_bbase<<<NBUK, 256, 0, stream>>>(bhistT, edgebase, NB_E);
  k_ebucket<<<NB_E, 256, 0, stream>>>(ei, ei + E, bhistT, bedges, E, NBUK);
  k_ebsort<<<NBUK, 256, 0, stream>>>(bedges, edgebase, bcnt, colidx, rowstart, dinv, N);
  // weight prep (fused)
  k_qprep<<<1, 256, 0, stream>>>(gat_w, att_s, att_d, Bq);
  k_wswz_all<<<16, 256, 0, stream>>>(w0, B0h, B0l, w1, Bw1h, Bw1l,
                                     w2, Bw2h, Bw2l, gat_w, Bgh, Bgl);

  // K1: h0' = f16(dinv * (x @ W0))
  k_gemm0_mfma<<<1024, 256, 0, stream>>>(x, B0h, B0l, dinv, hbuf, N, NT);
  // K2: x1 = relu(dinv*agg(h0')+b0); h1' = f16(dinv*(x1@W1))
  k_agg_gemm_mfma<<<NT, 1024, 0, stream>>>(hbuf, dinv, rowstart, colidx, b0,
                                           Bw1h, Bw1l, hbuf2, N);
  // K3
  k_agg_gemm_mfma<<<NT, 1024, 0, stream>>>(hbuf2, dinv, rowstart, colidx, b1,
                                           Bw2h, Bw2l, hbuf, N);
  // K4: x3 (f16) + attention logits via MFMA
  k_agg_gatpre_mfma<<<NT, 1024, 0, stream>>>(hbuf, dinv, rowstart, colidx, b2,
                                             Bq, xg, a_src, a_dst, N);
  // K5 fused: softmax-aggregate + 256->64 projection + bias + relu
  k_gat_fused<<<NT, 1024, 0, stream>>>(xg, a_src, a_dst, rowstart, colidx,
                                       Bgh, Bgl, gat_b, gatout, N);
  // fused pooling + MLP head
  k_pool_mlp<<<(B + 3) / 4, 256, 0, stream>>>(gatout, batch, l1w, l1b, l2w, l2b,
                                              (float*)d_out, N, B);
}